// Round 2
// baseline (156.575 us; speedup 1.0000x reference)
//
#include <hip/hip_runtime.h>
#include <hip/hip_bf16.h>
#include <stdint.h>

#define NROWS 8192
#define DIM   512
#define BM    256          // block tile (square)
#define BK    32           // K step per ring slot
#define NT    (DIM / BK)   // 16 K-tiles
#define SLOT_US 16384      // ushorts per ring slot (A 16KB + B 16KB)
#define A_US    8192       // A region within a slot (ushorts)

typedef short bf16x8 __attribute__((ext_vector_type(8)));
typedef float f32x4  __attribute__((ext_vector_type(4)));

// ---- order-preserving float<->uint encoding for atomicMax on floats ----
__device__ __forceinline__ unsigned fenc(float f) {
  unsigned u = __float_as_uint(f);
  return (u & 0x80000000u) ? ~u : (u | 0x80000000u);
}
__device__ __forceinline__ float fdec(unsigned u) {
  unsigned b = (u & 0x80000000u) ? (u ^ 0x80000000u) : ~u;
  return __uint_as_float(b);
}

// RNE f32 -> bf16 (no NaN inputs here)
__device__ __forceinline__ unsigned short f2bf(float x) {
  unsigned u = __float_as_uint(x);
  u += 0x7FFFu + ((u >> 16) & 1u);
  return (unsigned short)(u >> 16);
}

__device__ __forceinline__ void async16(const void* g, void* l) {
  __builtin_amdgcn_global_load_lds(
      (const __attribute__((address_space(1))) unsigned int*)g,
      (__attribute__((address_space(3))) unsigned int*)l, 16, 0, 0);
}

// ---- init the encoded max arrays (2 * 8192 entries) to enc(-2.0f) ----
__global__ void init_max_kernel(unsigned* __restrict__ enc) {
  int i = blockIdx.x * blockDim.x + threadIdx.x;
  if (i < 2 * NROWS) enc[i] = fenc(-2.0f);
}

// ---- normalize one row (512 f32) -> bf16, one block (128 thr) per row ----
__global__ __launch_bounds__(128) void normalize_kernel(
    const float* __restrict__ src, unsigned short* __restrict__ dst) {
  const int row = blockIdx.x;
  const int t = threadIdx.x;
  const float4* p = (const float4*)(src + (size_t)row * DIM);
  float4 v = p[t];
  float ss = v.x * v.x + v.y * v.y + v.z * v.z + v.w * v.w;
#pragma unroll
  for (int m = 1; m <= 32; m <<= 1) ss += __shfl_xor(ss, m);
  __shared__ float sred[2];
  if ((t & 63) == 0) sred[t >> 6] = ss;
  __syncthreads();
  const float tot = sred[0] + sred[1];
  const float sc = 1.0f / fmaxf(sqrtf(tot), 1e-8f);
  ushort4 o;
  o.x = f2bf(v.x * sc);
  o.y = f2bf(v.y * sc);
  o.z = f2bf(v.z * sc);
  o.w = f2bf(v.w * sc);
  ((ushort4*)(dst + (size_t)row * DIM))[t] = o;
}

// ---- bf16 MFMA GEMM (C = Xn * Yn^T), 256x256 tile, BK=32, 4-slot ring ----
// Fragment-major LDS: each 16x32 MFMA fragment is 1KB, stored lane-linear
// (lane l holds row l&15, k-slice (l>>4)*8). global_load_lds writes
// base + lane*16 -> gather the per-lane GLOBAL address instead; both the
// staging write and the ds_read_b128 (addr = frag_base + lane*16) are
// conflict-free by construction.
__global__ __launch_bounds__(512) void gemm_max_kernel(
    const unsigned short* __restrict__ Xn, const unsigned short* __restrict__ Yn,
    unsigned* __restrict__ rowmax, unsigned* __restrict__ colmax) {
  __shared__ unsigned short lds[4 * SLOT_US];  // 128 KB

  const int t = threadIdx.x;
  const int lane = t & 63;
  const int w = t >> 6;        // wave 0..7
  const int wr = w >> 2;       // 2 waves along M (each owns 128 rows)
  const int wc = w & 3;        // 4 waves along N (each owns 64 cols)

  // Bijective XCD-aware swizzle: grid = 32x32 tiles, 1024 blocks.
  // XCD x owns block-cols [4x, 4x+4); its 128 tiles walk 4 row-groups of
  // 8 rows x 4 cols (A-panel 2MB + B-panel 1MB resident per super-block).
  const int raw = blockIdx.x;
  const int xcd = raw & 7;
  const int l = raw >> 3;                       // 0..127
  const int brow = ((l >> 5) * 8 + (l & 7)) * BM;
  const int bcol = (xcd * 4 + ((l >> 3) & 3)) * BM;

  // per-lane gather source: fragment f covers rows f*16..f*16+15.
  // wave w stages fragments f=w (rows w*16+) and f=w+8 (rows 128+w*16+).
  const int fr = lane & 15;
  const int fk = (lane >> 4) * 8;
  const unsigned short* gA0 = Xn + (size_t)(brow + w * 16 + fr) * DIM + fk;
  const unsigned short* gB0 = Yn + (size_t)(bcol + w * 16 + fr) * DIM + fk;

  f32x4 acc[8][4];
#pragma unroll
  for (int m = 0; m < 8; ++m)
#pragma unroll
    for (int n = 0; n < 4; ++n) acc[m][n] = (f32x4){0.f, 0.f, 0.f, 0.f};

  auto stage = [&](int tt) {
    const int s = tt & 3;
    const size_t ko = (size_t)tt * BK;
    async16(gA0 + ko, &lds[s * SLOT_US + w * 512]);
    async16(gA0 + (size_t)128 * DIM + ko, &lds[s * SLOT_US + (w + 8) * 512]);
    async16(gB0 + ko, &lds[s * SLOT_US + A_US + w * 512]);
    async16(gB0 + (size_t)128 * DIM + ko, &lds[s * SLOT_US + A_US + (w + 8) * 512]);
  };

  auto compute = [&](int tt) {
    const int s = tt & 3;
    const unsigned short* As = &lds[s * SLOT_US];
    const unsigned short* Bs = &lds[s * SLOT_US + A_US];
    bf16x8 b[4];
#pragma unroll
    for (int n = 0; n < 4; ++n)
      b[n] = *(const bf16x8*)(Bs + (wc * 4 + n) * 512 + lane * 8);
    __builtin_amdgcn_s_setprio(1);
#pragma unroll
    for (int m = 0; m < 8; ++m) {
      bf16x8 a = *(const bf16x8*)(As + (wr * 8 + m) * 512 + lane * 8);
#pragma unroll
      for (int n = 0; n < 4; ++n)
        acc[m][n] = __builtin_amdgcn_mfma_f32_16x16x32_bf16(a, b[n], acc[m][n], 0, 0, 0);
    }
    __builtin_amdgcn_s_setprio(0);
  };

  // prologue: 3 tiles in flight
  stage(0); stage(1); stage(2);

  // steady state: issue tile tt+3, wait own tile-tt loads (12 newer stay in
  // flight -> no drain), barrier (all waves' slices landed), compute, then
  // lgkmcnt(0)+barrier so the slot can be rewritten next iteration.
  for (int tt = 0; tt < NT - 3; ++tt) {
    stage(tt + 3);
    asm volatile("s_waitcnt vmcnt(12)" ::: "memory");
    __builtin_amdgcn_s_barrier();
    compute(tt);
    asm volatile("s_waitcnt lgkmcnt(0)" ::: "memory");
    __builtin_amdgcn_sched_barrier(0);
    __builtin_amdgcn_s_barrier();
  }
  // tail: no more staging, no slot reuse -> only data-ready waits
  asm volatile("s_waitcnt vmcnt(8)" ::: "memory");
  __builtin_amdgcn_s_barrier();
  compute(NT - 3);
  asm volatile("s_waitcnt vmcnt(4)" ::: "memory");
  __builtin_amdgcn_s_barrier();
  compute(NT - 2);
  asm volatile("s_waitcnt vmcnt(0)" ::: "memory");
  __builtin_amdgcn_s_barrier();
  compute(NT - 1);

  // ---- epilogue: C/D layout col=lane&15, row=(lane>>4)*4+reg ----
#pragma unroll
  for (int m = 0; m < 8; ++m) {
    f32x4 rm = acc[m][0];
#pragma unroll
    for (int n = 1; n < 4; ++n) {
      rm[0] = fmaxf(rm[0], acc[m][n][0]);
      rm[1] = fmaxf(rm[1], acc[m][n][1]);
      rm[2] = fmaxf(rm[2], acc[m][n][2]);
      rm[3] = fmaxf(rm[3], acc[m][n][3]);
    }
#pragma unroll
    for (int r = 0; r < 4; ++r) {
      float v = rm[r];
      v = fmaxf(v, __shfl_xor(v, 1));
      v = fmaxf(v, __shfl_xor(v, 2));
      v = fmaxf(v, __shfl_xor(v, 4));
      v = fmaxf(v, __shfl_xor(v, 8));
      if ((lane & 15) == 0) {
        const int grow = brow + wr * 128 + m * 16 + (lane >> 4) * 4 + r;
        atomicMax(rowmax + grow, fenc(v));
      }
    }
  }
#pragma unroll
  for (int n = 0; n < 4; ++n) {
    float cm = -2.0f;
#pragma unroll
    for (int m = 0; m < 8; ++m) {
      cm = fmaxf(cm, acc[m][n][0]);
      cm = fmaxf(cm, acc[m][n][1]);
      cm = fmaxf(cm, acc[m][n][2]);
      cm = fmaxf(cm, acc[m][n][3]);
    }
    cm = fmaxf(cm, __shfl_xor(cm, 16));
    cm = fmaxf(cm, __shfl_xor(cm, 32));
    if (lane < 16) {
      const int gcol = bcol + wc * 64 + n * 16 + lane;
      atomicMax(colmax + gcol, fenc(cm));
    }
  }
}

// ---- entropy: out[b] = -sum( exp(lp)*lp ), lp = -0.5*z^2 + 0.285034... ----
__global__ __launch_bounds__(256) void entropy_kernel(
    const unsigned* __restrict__ enc, float* __restrict__ out) {
  const int which = blockIdx.x;  // 0 = rowmax, 1 = colmax
  const unsigned* e = enc + which * NROWS;
  float s = 0.0f;
  for (int i = threadIdx.x; i < NROWS; i += 256) {
    const float x = fdec(e[i]);
    const float z = (x - 1.0f) * (1.0f / 0.3f);
    const float lp = -0.5f * z * z + 0.2850342711439819f;  // -log(0.3)-0.5*log(2*pi)
    s += expf(lp) * lp;
  }
#pragma unroll
  for (int m = 1; m <= 32; m <<= 1) s += __shfl_xor(s, m);
  __shared__ float sr[4];
  if ((threadIdx.x & 63) == 0) sr[threadIdx.x >> 6] = s;
  __syncthreads();
  if (threadIdx.x == 0) out[which] = -(sr[0] + sr[1] + sr[2] + sr[3]);
}

extern "C" void kernel_launch(void* const* d_in, const int* in_sizes, int n_in,
                              void* d_out, int out_size, void* d_ws, size_t ws_size,
                              hipStream_t stream) {
  const float* ex = (const float*)d_in[0];
  const float* ey = (const float*)d_in[1];

  unsigned short* Xn = (unsigned short*)d_ws;                 // 8 MB
  unsigned short* Yn = Xn + (size_t)NROWS * DIM;              // 8 MB
  unsigned* enc = (unsigned*)(Yn + (size_t)NROWS * DIM);      // 2*8192 u32
  float* out = (float*)d_out;

  hipLaunchKernelGGL(init_max_kernel, dim3(64), dim3(256), 0, stream, enc);
  hipLaunchKernelGGL(normalize_kernel, dim3(NROWS), dim3(128), 0, stream, ex, Xn);
  hipLaunchKernelGGL(normalize_kernel, dim3(NROWS), dim3(128), 0, stream, ey, Yn);
  hipLaunchKernelGGL(gemm_max_kernel, dim3(32 * 32), dim3(512), 0, stream,
                     Xn, Yn, enc, enc + NROWS);
  hipLaunchKernelGGL(entropy_kernel, dim3(2), dim3(256), 0, stream, enc, out);
}

// Round 3
// 131.338 us; speedup vs baseline: 1.1921x; 1.1921x over previous
//
#include <hip/hip_runtime.h>
#include <hip/hip_bf16.h>
#include <stdint.h>

#define NROWS 8192
#define DIM   512
#define BM    256
#define BK    64
#define NSTEP (DIM / BK)   // 8
#define FRAG_US 512        // ushorts per 16x32 bf16 fragment (1 KB)
#define MAT_US  16384      // 32 fragments (256 rows x 64 k) per matrix per buffer

typedef unsigned short u16;
typedef short bf16x8 __attribute__((ext_vector_type(8)));
typedef float f32x4  __attribute__((ext_vector_type(4)));
typedef unsigned short u16x8 __attribute__((ext_vector_type(8)));

// ---- order-preserving float<->uint encoding for atomicMax on floats ----
__device__ __forceinline__ unsigned fenc(float f) {
  unsigned u = __float_as_uint(f);
  return (u & 0x80000000u) ? ~u : (u | 0x80000000u);
}
__device__ __forceinline__ float fdec(unsigned u) {
  unsigned b = (u & 0x80000000u) ? (u ^ 0x80000000u) : ~u;
  return __uint_as_float(b);
}

// RNE f32 -> bf16 (no NaN inputs here)
__device__ __forceinline__ u16 f2bf(float x) {
  unsigned u = __float_as_uint(x);
  u += 0x7FFFu + ((u >> 16) & 1u);
  return (u16)(u >> 16);
}

__device__ __forceinline__ void async16(const void* g, void* l) {
  __builtin_amdgcn_global_load_lds(
      (const __attribute__((address_space(1))) unsigned int*)g,
      (__attribute__((address_space(3))) unsigned int*)l, 16, 0, 0);
}

// ---- init the encoded max arrays (2 * 8192 entries) to enc(-2.0f) ----
__global__ void init_max_kernel(unsigned* __restrict__ enc) {
  int i = blockIdx.x * blockDim.x + threadIdx.x;
  if (i < 2 * NROWS) enc[i] = fenc(-2.0f);
}

// ---- normalize 16 rows (one panel) -> bf16 in FRAGMENT-MAJOR layout ----
// Fragment (panel P, q): 1KB at (P*16+q)*512 ushorts; lane l holds
// row P*16+(l&15), k = q*32 + (l>>4)*8 + j  (natural order, A/B consistent).
__global__ __launch_bounds__(512) void normf_kernel(
    const float* __restrict__ src, u16* __restrict__ dst) {
  const int p = blockIdx.x;
  const int t = threadIdx.x, lane = t & 63, w = t >> 6;
  const int fr = lane & 15, hi = lane >> 4;
  __shared__ float part[16][8];
  float e[2][8];
  float ss = 0.f;
#pragma unroll
  for (int c = 0; c < 2; ++c) {
    const int q = w + c * 8;
    const float* g = src + (size_t)(p * 16 + fr) * DIM + q * 32 + hi * 8;
    float4 v0 = *(const float4*)g;
    float4 v1 = *(const float4*)(g + 4);
    e[c][0] = v0.x; e[c][1] = v0.y; e[c][2] = v0.z; e[c][3] = v0.w;
    e[c][4] = v1.x; e[c][5] = v1.y; e[c][6] = v1.z; e[c][7] = v1.w;
#pragma unroll
    for (int j = 0; j < 8; ++j) ss += e[c][j] * e[c][j];
  }
  ss += __shfl_xor(ss, 16);
  ss += __shfl_xor(ss, 32);
  if (lane < 16) part[lane][w] = ss;
  __syncthreads();
  float tot = 0.f;
#pragma unroll
  for (int i = 0; i < 8; ++i) tot += part[fr][i];
  const float sc = 1.0f / fmaxf(sqrtf(tot), 1e-8f);
#pragma unroll
  for (int c = 0; c < 2; ++c) {
    const int q = w + c * 8;
    u16x8 o;
#pragma unroll
    for (int j = 0; j < 8; ++j) o[j] = f2bf(e[c][j] * sc);
    *(u16x8*)(dst + ((size_t)(p * 16 + q) * 64 + lane) * 8) = o;
  }
}

// ---- 256x256 MFMA GEMM, BK=64, dbuf, 4-phase/K-step, fused row/col max ----
#define LDA_(MH, KK)                                                          \
  _Pragma("unroll") for (int m_ = 0; m_ < 4; ++m_)                            \
      Ar[m_] = *(const bf16x8*)(Ab + ((wr * 8 + MH * 4 + m_) * 2 + KK) * FRAG_US + lane * 8);
#define LDB_(KK)                                                              \
  _Pragma("unroll") for (int n_ = 0; n_ < 4; ++n_)                            \
      Br[n_] = *(const bf16x8*)(Bb + ((wc * 4 + n_) * 2 + KK) * FRAG_US + lane * 8);
#define MM_(MH)                                                               \
  __builtin_amdgcn_s_setprio(1);                                              \
  _Pragma("unroll") for (int m_ = 0; m_ < 4; ++m_)                            \
      _Pragma("unroll") for (int n_ = 0; n_ < 4; ++n_)                        \
          acc[MH * 4 + m_][n_] = __builtin_amdgcn_mfma_f32_16x16x32_bf16(     \
              Ar[m_], Br[n_], acc[MH * 4 + m_][n_], 0, 0, 0);                 \
  __builtin_amdgcn_s_setprio(0);
#define SB_ __builtin_amdgcn_sched_barrier(0)
#define BAR_ __builtin_amdgcn_s_barrier()
#define LGKM0_ asm volatile("s_waitcnt lgkmcnt(0)" ::: "memory")
#define VM4_ asm volatile("s_waitcnt vmcnt(4)" ::: "memory")

__global__ __launch_bounds__(512, 2) void gemm_max_kernel(
    const u16* __restrict__ Xf, const u16* __restrict__ Yf,
    unsigned* __restrict__ rowmax, unsigned* __restrict__ colmax) {
  __shared__ u16 lds[2][2][MAT_US];  // [buf][A/B][frags] = 128 KB

  const int t = threadIdx.x, lane = t & 63, w = t >> 6;
  const int wr = w >> 2, wc = w & 3;  // 2x4 wave grid; wave owns 128x64 out

  // bijective XCD swizzle (1024 blocks % 8 == 0): per XCD-round, 8 brow x 4 bcol
  const int raw = blockIdx.x, xcd = raw & 7, l = raw >> 3;
  const int brow = ((l >> 5) * 8 + (l & 7)) * BM;
  const int bcol = (xcd * 4 + ((l >> 3) & 3)) * BM;
  const int browP = brow >> 4, bcolP = bcol >> 4;

  f32x4 acc[8][4];
#pragma unroll
  for (int m = 0; m < 8; ++m)
#pragma unroll
    for (int n = 0; n < 4; ++n) acc[m][n] = (f32x4){0.f, 0.f, 0.f, 0.f};

  // linear staging sources: wave w stages panels {w, w+8}; 1KB contiguous/instr
  const u16* gA0 = Xf + (size_t)(browP + w) * 16 * FRAG_US + lane * 8;
  const u16* gA1 = Xf + (size_t)(browP + w + 8) * 16 * FRAG_US + lane * 8;
  const u16* gB0 = Yf + (size_t)(bcolP + w) * 16 * FRAG_US + lane * 8;
  const u16* gB1 = Yf + (size_t)(bcolP + w + 8) * 16 * FRAG_US + lane * 8;

  // prologue: stage step 0 (order: Bkk0, Akk0, Bkk1, Akk1), wait kk0
  async16(gB0, &lds[0][1][(w * 2 + 0) * FRAG_US]);
  async16(gB1, &lds[0][1][((w + 8) * 2 + 0) * FRAG_US]);
  async16(gA0, &lds[0][0][(w * 2 + 0) * FRAG_US]);
  async16(gA1, &lds[0][0][((w + 8) * 2 + 0) * FRAG_US]);
  async16(gB0 + FRAG_US, &lds[0][1][(w * 2 + 1) * FRAG_US]);
  async16(gB1 + FRAG_US, &lds[0][1][((w + 8) * 2 + 1) * FRAG_US]);
  async16(gA0 + FRAG_US, &lds[0][0][(w * 2 + 1) * FRAG_US]);
  async16(gA1 + FRAG_US, &lds[0][0][((w + 8) * 2 + 1) * FRAG_US]);
  VM4_; SB_; BAR_;

#pragma unroll 1
  for (int tt = 0; tt < NSTEP - 1; ++tt) {
    const u16* Ab = &lds[tt & 1][0][0];
    const u16* Bb = &lds[tt & 1][1][0];
    u16* An = &lds[(tt + 1) & 1][0][0];
    u16* Bn = &lds[(tt + 1) & 1][1][0];
    const int go = (tt + 1) * 2 * FRAG_US;
    bf16x8 Ar[4], Br[4];
    // phase 0: reads kk0 (cleared at prev step ph3), stage B kk0 of t+1
    LDB_(0); LDA_(0, 0);
    async16(gB0 + go, Bn + (w * 2 + 0) * FRAG_US);
    async16(gB1 + go, Bn + ((w + 8) * 2 + 0) * FRAG_US);
    SB_; BAR_; LGKM0_; SB_;
    MM_(0);
    BAR_; SB_;
    // phase 1: stage A kk0; vmcnt(4) clears THIS step's kk1 for ph2
    LDA_(1, 0);
    async16(gA0 + go, An + (w * 2 + 0) * FRAG_US);
    async16(gA1 + go, An + ((w + 8) * 2 + 0) * FRAG_US);
    VM4_; SB_; BAR_; LGKM0_; SB_;
    MM_(1);
    BAR_; SB_;
    // phase 2: reads kk1, stage B kk1 of t+1
    LDB_(1); LDA_(0, 1);
    async16(gB0 + go + FRAG_US, Bn + (w * 2 + 1) * FRAG_US);
    async16(gB1 + go + FRAG_US, Bn + ((w + 8) * 2 + 1) * FRAG_US);
    SB_; BAR_; LGKM0_; SB_;
    MM_(0);
    BAR_; SB_;
    // phase 3: stage A kk1; vmcnt(4) clears t+1's kk0 for next ph0
    LDA_(1, 1);
    async16(gA0 + go + FRAG_US, An + (w * 2 + 1) * FRAG_US);
    async16(gA1 + go + FRAG_US, An + ((w + 8) * 2 + 1) * FRAG_US);
    VM4_; SB_; BAR_; LGKM0_; SB_;
    MM_(1);
    BAR_; SB_;
  }
  {  // tail step (tt = NSTEP-1): no staging; drain kk1 at ph1
    const u16* Ab = &lds[(NSTEP - 1) & 1][0][0];
    const u16* Bb = &lds[(NSTEP - 1) & 1][1][0];
    bf16x8 Ar[4], Br[4];
    LDB_(0); LDA_(0, 0);
    SB_; BAR_; LGKM0_; SB_; MM_(0); BAR_; SB_;
    LDA_(1, 0);
    asm volatile("s_waitcnt vmcnt(0)" ::: "memory");
    SB_; BAR_; LGKM0_; SB_; MM_(1); BAR_; SB_;
    LDB_(1); LDA_(0, 1);
    SB_; BAR_; LGKM0_; SB_; MM_(0); BAR_; SB_;
    LDA_(1, 1);
    SB_; BAR_; LGKM0_; SB_; MM_(1);
  }

  // ---- epilogue: C/D layout col=lane&15, row=(lane>>4)*4+reg ----
#pragma unroll
  for (int m = 0; m < 8; ++m) {
    f32x4 rm = acc[m][0];
#pragma unroll
    for (int n = 1; n < 4; ++n) {
      rm[0] = fmaxf(rm[0], acc[m][n][0]);
      rm[1] = fmaxf(rm[1], acc[m][n][1]);
      rm[2] = fmaxf(rm[2], acc[m][n][2]);
      rm[3] = fmaxf(rm[3], acc[m][n][3]);
    }
#pragma unroll
    for (int r = 0; r < 4; ++r) {
      float v = rm[r];
      v = fmaxf(v, __shfl_xor(v, 1));
      v = fmaxf(v, __shfl_xor(v, 2));
      v = fmaxf(v, __shfl_xor(v, 4));
      v = fmaxf(v, __shfl_xor(v, 8));
      if ((lane & 15) == 0) {
        const int grow = brow + wr * 128 + m * 16 + (lane >> 4) * 4 + r;
        atomicMax(rowmax + grow, fenc(v));
      }
    }
  }
#pragma unroll
  for (int n = 0; n < 4; ++n) {
    float cm = -2.0f;
#pragma unroll
    for (int m = 0; m < 8; ++m) {
      cm = fmaxf(cm, acc[m][n][0]);
      cm = fmaxf(cm, acc[m][n][1]);
      cm = fmaxf(cm, acc[m][n][2]);
      cm = fmaxf(cm, acc[m][n][3]);
    }
    cm = fmaxf(cm, __shfl_xor(cm, 16));
    cm = fmaxf(cm, __shfl_xor(cm, 32));
    if (lane < 16) {
      const int gcol = bcol + wc * 64 + n * 16 + lane;
      atomicMax(colmax + gcol, fenc(cm));
    }
  }
}

// ---- entropy: out[b] = -sum( exp(lp)*lp ), lp = -0.5*z^2 + 0.285034... ----
__global__ __launch_bounds__(256) void entropy_kernel(
    const unsigned* __restrict__ enc, float* __restrict__ out) {
  const int which = blockIdx.x;
  const unsigned* e = enc + which * NROWS;
  float s = 0.0f;
  for (int i = threadIdx.x; i < NROWS; i += 256) {
    const float x = fdec(e[i]);
    const float z = (x - 1.0f) * (1.0f / 0.3f);
    const float lp = -0.5f * z * z + 0.2850342711439819f;
    s += expf(lp) * lp;
  }
#pragma unroll
  for (int m = 1; m <= 32; m <<= 1) s += __shfl_xor(s, m);
  __shared__ float sr[4];
  if ((threadIdx.x & 63) == 0) sr[threadIdx.x >> 6] = s;
  __syncthreads();
  if (threadIdx.x == 0) out[which] = -(sr[0] + sr[1] + sr[2] + sr[3]);
}

extern "C" void kernel_launch(void* const* d_in, const int* in_sizes, int n_in,
                              void* d_out, int out_size, void* d_ws, size_t ws_size,
                              hipStream_t stream) {
  const float* ex = (const float*)d_in[0];
  const float* ey = (const float*)d_in[1];

  u16* Xf = (u16*)d_ws;                                  // 8 MB fragment-major
  u16* Yf = Xf + (size_t)NROWS * DIM;                    // 8 MB
  unsigned* enc = (unsigned*)(Yf + (size_t)NROWS * DIM); // 2*8192 u32
  float* out = (float*)d_out;

  hipLaunchKernelGGL(init_max_kernel, dim3(64), dim3(256), 0, stream, enc);
  hipLaunchKernelGGL(normf_kernel, dim3(NROWS / 16), dim3(512), 0, stream, ex, Xf);
  hipLaunchKernelGGL(normf_kernel, dim3(NROWS / 16), dim3(512), 0, stream, ey, Yf);
  hipLaunchKernelGGL(gemm_max_kernel, dim3(32 * 32), dim3(512), 0, stream,
                     Xf, Yf, enc, enc + NROWS);
  hipLaunchKernelGGL(entropy_kernel, dim3(2), dim3(256), 0, stream, enc, out);
}

// Round 4
// 128.952 us; speedup vs baseline: 1.2142x; 1.0185x over previous
//
#include <hip/hip_runtime.h>
#include <hip/hip_bf16.h>
#include <stdint.h>

#define NROWS 8192
#define DIM   512
#define BM    256
#define HT    16            // half-K-tiles (BK=32 each)
#define FRAG_US 512         // ushorts per 16x32 bf16 fragment (1 KB)
#define SLOT_US 16384       // 32 KB slot: A 16 KB + B 16 KB
#define SLOT_B  8192        // B offset within slot (ushorts)

typedef unsigned short u16;
typedef short bf16x8 __attribute__((ext_vector_type(8)));
typedef float f32x4  __attribute__((ext_vector_type(4)));
typedef unsigned short u16x8 __attribute__((ext_vector_type(8)));

// ---- order-preserving float<->uint encoding for atomicMax on floats ----
__device__ __forceinline__ unsigned fenc(float f) {
  unsigned u = __float_as_uint(f);
  return (u & 0x80000000u) ? ~u : (u | 0x80000000u);
}
__device__ __forceinline__ float fdec(unsigned u) {
  unsigned b = (u & 0x80000000u) ? (u ^ 0x80000000u) : ~u;
  return __uint_as_float(b);
}

// RNE f32 -> bf16 (no NaN inputs here)
__device__ __forceinline__ u16 f2bf(float x) {
  unsigned u = __float_as_uint(x);
  u += 0x7FFFu + ((u >> 16) & 1u);
  return (u16)(u >> 16);
}

__device__ __forceinline__ void async16(const void* g, void* l) {
  __builtin_amdgcn_global_load_lds(
      (const __attribute__((address_space(1))) unsigned int*)g,
      (__attribute__((address_space(3))) unsigned int*)l, 16, 0, 0);
}

// ---- normalize 16 rows (one panel) -> bf16 in FRAGMENT-MAJOR layout ----
// Fragment (panel P, q): 1KB at (P*16+q)*512 ushorts; lane l holds
// row P*16+(l&15), k = q*32 + (l>>4)*8 + j. Optionally inits the max arrays.
__global__ __launch_bounds__(512) void normf_kernel(
    const float* __restrict__ src, u16* __restrict__ dst,
    unsigned* __restrict__ enc_init) {
  const int p = blockIdx.x;
  const int t = threadIdx.x, lane = t & 63, w = t >> 6;
  const int fr = lane & 15, hi = lane >> 4;
  if (enc_init) {
    const int i = p * 512 + t;
    if (i < 2 * NROWS) enc_init[i] = fenc(-2.0f);
  }
  __shared__ float part[16][8];
  float e[2][8];
  float ss = 0.f;
#pragma unroll
  for (int c = 0; c < 2; ++c) {
    const int q = w + c * 8;
    const float* g = src + (size_t)(p * 16 + fr) * DIM + q * 32 + hi * 8;
    float4 v0 = *(const float4*)g;
    float4 v1 = *(const float4*)(g + 4);
    e[c][0] = v0.x; e[c][1] = v0.y; e[c][2] = v0.z; e[c][3] = v0.w;
    e[c][4] = v1.x; e[c][5] = v1.y; e[c][6] = v1.z; e[c][7] = v1.w;
#pragma unroll
    for (int j = 0; j < 8; ++j) ss += e[c][j] * e[c][j];
  }
  ss += __shfl_xor(ss, 16);
  ss += __shfl_xor(ss, 32);
  if (lane < 16) part[lane][w] = ss;
  __syncthreads();
  float tot = 0.f;
#pragma unroll
  for (int i = 0; i < 8; ++i) tot += part[fr][i];
  const float sc = 1.0f / fmaxf(sqrtf(tot), 1e-8f);
#pragma unroll
  for (int c = 0; c < 2; ++c) {
    const int q = w + c * 8;
    u16x8 o;
#pragma unroll
    for (int j = 0; j < 8; ++j) o[j] = f2bf(e[c][j] * sc);
    *(u16x8*)(dst + ((size_t)(p * 16 + q) * 64 + lane) * 8) = o;
  }
}

// ---- 256x256 MFMA GEMM, 4-slot half-K-tile ring, fused row/col max ----
#define BAR_ __builtin_amdgcn_s_barrier()
#define LGKM0_ asm volatile("s_waitcnt lgkmcnt(0)" ::: "memory")
#define VMW8_ asm volatile("s_waitcnt vmcnt(8)" ::: "memory")
#define VMW4_ asm volatile("s_waitcnt vmcnt(4)" ::: "memory")
#define VMW0_ asm volatile("s_waitcnt vmcnt(0)" ::: "memory")

#define LDB4(S)                                                               \
  _Pragma("unroll") for (int n_ = 0; n_ < 4; ++n_)                            \
      Br[n_] = *(const bf16x8*)(&lds[(S) * SLOT_US + SLOT_B +                 \
                                     (wc * 4 + n_) * FRAG_US + lane * 8]);
#define LDA4(S, G)                                                            \
  _Pragma("unroll") for (int m_ = 0; m_ < 4; ++m_)                            \
      Ar[m_] = *(const bf16x8*)(&lds[(S) * SLOT_US +                          \
                                     (wr * 8 + (G) * 4 + m_) * FRAG_US + lane * 8]);
#define MM16(G)                                                               \
  __builtin_amdgcn_s_setprio(1);                                              \
  _Pragma("unroll") for (int m_ = 0; m_ < 4; ++m_)                            \
      _Pragma("unroll") for (int n_ = 0; n_ < 4; ++n_)                        \
          acc[(G) * 4 + m_][n_] = __builtin_amdgcn_mfma_f32_16x16x32_bf16(    \
              Ar[m_], Br[n_], acc[(G) * 4 + m_][n_], 0, 0, 0);                \
  __builtin_amdgcn_s_setprio(0);

// One half-K-tile: 2 phases. B frags register-reused across both phases.
#define HALF_(H, STG, VMW)                                                    \
  {                                                                           \
    const int S_ = (H) & 3, S3_ = ((H) + 3) & 3;                              \
    const size_t ho_ = (size_t)((H) + 3) * FRAG_US;                           \
    bf16x8 Ar[4], Br[4];                                                      \
    LDB4(S_); LDA4(S_, 0);                                                    \
    if (STG) {                                                                \
      async16(gB0 + ho_, &lds[S3_ * SLOT_US + SLOT_B + w * FRAG_US]);         \
      async16(gB1 + ho_, &lds[S3_ * SLOT_US + SLOT_B + (w + 8) * FRAG_US]);   \
    }                                                                         \
    BAR_; LGKM0_;                                                             \
    MM16(0);                                                                  \
    BAR_;                                                                     \
    LDA4(S_, 1);                                                              \
    if (STG) {                                                                \
      async16(gA0 + ho_, &lds[S3_ * SLOT_US + w * FRAG_US]);                  \
      async16(gA1 + ho_, &lds[S3_ * SLOT_US + (w + 8) * FRAG_US]);            \
    }                                                                         \
    VMW;                                                                      \
    BAR_; LGKM0_;                                                             \
    MM16(1);                                                                  \
    BAR_;                                                                     \
  }

__global__ __launch_bounds__(512, 2) void gemm_max_kernel(
    const u16* __restrict__ Xf, const u16* __restrict__ Yf,
    unsigned* __restrict__ rowmax, unsigned* __restrict__ colmax) {
  __shared__ u16 lds[4 * SLOT_US];  // 128 KB

  const int t = threadIdx.x, lane = t & 63, w = t >> 6;
  const int wr = w >> 2, wc = w & 3;  // 2x4 wave grid; wave owns 128x64 out

  // bijective XCD swizzle (1024 blocks % 8 == 0)
  const int raw = blockIdx.x, xcd = raw & 7, l = raw >> 3;
  const int brow = ((l >> 5) * 8 + (l & 7)) * BM;
  const int bcol = (xcd * 4 + ((l >> 3) & 3)) * BM;
  const int browP = brow >> 4, bcolP = bcol >> 4;

  f32x4 acc[8][4];
#pragma unroll
  for (int m = 0; m < 8; ++m)
#pragma unroll
    for (int n = 0; n < 4; ++n) acc[m][n] = (f32x4){0.f, 0.f, 0.f, 0.f};

  // linear staging sources: wave w stages panel-frags {w, w+8}; 1KB/instr
  const u16* gA0 = Xf + (size_t)(browP + w) * 16 * FRAG_US + lane * 8;
  const u16* gA1 = Xf + (size_t)(browP + w + 8) * 16 * FRAG_US + lane * 8;
  const u16* gB0 = Yf + (size_t)(bcolP + w) * 16 * FRAG_US + lane * 8;
  const u16* gB1 = Yf + (size_t)(bcolP + w + 8) * 16 * FRAG_US + lane * 8;

  // prologue: stage slots 0..2 (12 loads/wave in flight), wait slot 0 (=8 left)
#pragma unroll
  for (int s = 0; s < 3; ++s) {
    const size_t o = (size_t)s * FRAG_US;
    async16(gB0 + o, &lds[s * SLOT_US + SLOT_B + w * FRAG_US]);
    async16(gB1 + o, &lds[s * SLOT_US + SLOT_B + (w + 8) * FRAG_US]);
    async16(gA0 + o, &lds[s * SLOT_US + w * FRAG_US]);
    async16(gA1 + o, &lds[s * SLOT_US + (w + 8) * FRAG_US]);
  }
  VMW8_;
  BAR_;

  // steady state: stage slot h+3, hold 2 slots outstanding (vmcnt(8))
#pragma unroll 1
  for (int h = 0; h < HT - 3; ++h) HALF_(h, 1, VMW8_);
  // tail: drain 8 -> 4 -> 0
  HALF_(HT - 3, 0, VMW4_);
  HALF_(HT - 2, 0, VMW0_);
  HALF_(HT - 1, 0, ;);

  // ---- epilogue: C/D layout col=lane&15, row=(lane>>4)*4+reg ----
#pragma unroll
  for (int m = 0; m < 8; ++m) {
    f32x4 rm = acc[m][0];
#pragma unroll
    for (int n = 1; n < 4; ++n) {
      rm[0] = fmaxf(rm[0], acc[m][n][0]);
      rm[1] = fmaxf(rm[1], acc[m][n][1]);
      rm[2] = fmaxf(rm[2], acc[m][n][2]);
      rm[3] = fmaxf(rm[3], acc[m][n][3]);
    }
#pragma unroll
    for (int r = 0; r < 4; ++r) {
      float v = rm[r];
      v = fmaxf(v, __shfl_xor(v, 1));
      v = fmaxf(v, __shfl_xor(v, 2));
      v = fmaxf(v, __shfl_xor(v, 4));
      v = fmaxf(v, __shfl_xor(v, 8));
      if ((lane & 15) == 0) {
        const int grow = brow + wr * 128 + m * 16 + (lane >> 4) * 4 + r;
        atomicMax(rowmax + grow, fenc(v));
      }
    }
  }
#pragma unroll
  for (int n = 0; n < 4; ++n) {
    float cm = -2.0f;
#pragma unroll
    for (int m = 0; m < 8; ++m) {
      cm = fmaxf(cm, acc[m][n][0]);
      cm = fmaxf(cm, acc[m][n][1]);
      cm = fmaxf(cm, acc[m][n][2]);
      cm = fmaxf(cm, acc[m][n][3]);
    }
    cm = fmaxf(cm, __shfl_xor(cm, 16));
    cm = fmaxf(cm, __shfl_xor(cm, 32));
    if (lane < 16) {
      const int gcol = bcol + wc * 64 + n * 16 + lane;
      atomicMax(colmax + gcol, fenc(cm));
    }
  }
}

// ---- entropy: out[b] = -sum( exp(lp)*lp ), lp = -0.5*z^2 + 0.285034... ----
__global__ __launch_bounds__(256) void entropy_kernel(
    const unsigned* __restrict__ enc, float* __restrict__ out) {
  const int which = blockIdx.x;
  const unsigned* e = enc + which * NROWS;
  float s = 0.0f;
  for (int i = threadIdx.x; i < NROWS; i += 256) {
    const float x = fdec(e[i]);
    const float z = (x - 1.0f) * (1.0f / 0.3f);
    const float lp = -0.5f * z * z + 0.2850342711439819f;
    s += expf(lp) * lp;
  }
#pragma unroll
  for (int m = 1; m <= 32; m <<= 1) s += __shfl_xor(s, m);
  __shared__ float sr[4];
  if ((threadIdx.x & 63) == 0) sr[threadIdx.x >> 6] = s;
  __syncthreads();
  if (threadIdx.x == 0) out[which] = -(sr[0] + sr[1] + sr[2] + sr[3]);
}

extern "C" void kernel_launch(void* const* d_in, const int* in_sizes, int n_in,
                              void* d_out, int out_size, void* d_ws, size_t ws_size,
                              hipStream_t stream) {
  const float* ex = (const float*)d_in[0];
  const float* ey = (const float*)d_in[1];

  u16* Xf = (u16*)d_ws;                                  // 8 MB fragment-major
  u16* Yf = Xf + (size_t)NROWS * DIM;                    // 8 MB
  unsigned* enc = (unsigned*)(Yf + (size_t)NROWS * DIM); // 2*8192 u32
  float* out = (float*)d_out;

  hipLaunchKernelGGL(normf_kernel, dim3(NROWS / 16), dim3(512), 0, stream, ex, Xf, enc);
  hipLaunchKernelGGL(normf_kernel, dim3(NROWS / 16), dim3(512), 0, stream, ey, Yf, (unsigned*)nullptr);
  hipLaunchKernelGGL(gemm_max_kernel, dim3(32 * 32), dim3(512), 0, stream,
                     Xf, Yf, enc, enc + NROWS);
  hipLaunchKernelGGL(entropy_kernel, dim3(2), dim3(256), 0, stream, enc, out);
}

// Round 5
// 124.501 us; speedup vs baseline: 1.2576x; 1.0358x over previous
//
#include <hip/hip_runtime.h>
#include <hip/hip_bf16.h>
#include <stdint.h>

#define NROWS 8192
#define DIM   512
#define NQ    16           // k-frags per panel (DIM/32)
#define NSTEP 16           // K-steps (BK=32)

typedef unsigned short u16;
typedef short bf16x8 __attribute__((ext_vector_type(8)));
typedef float f32x4  __attribute__((ext_vector_type(4)));
typedef unsigned short u16x8 __attribute__((ext_vector_type(8)));

// ---- order-preserving float<->uint encoding for atomicMax on floats ----
__device__ __forceinline__ unsigned fenc(float f) {
  unsigned u = __float_as_uint(f);
  return (u & 0x80000000u) ? ~u : (u | 0x80000000u);
}
__device__ __forceinline__ float fdec(unsigned u) {
  unsigned b = (u & 0x80000000u) ? (u ^ 0x80000000u) : ~u;
  return __uint_as_float(b);
}

// RNE f32 -> bf16 (no NaN inputs here)
__device__ __forceinline__ u16 f2bf(float x) {
  unsigned u = __float_as_uint(x);
  u += 0x7FFFu + ((u >> 16) & 1u);
  return (u16)(u >> 16);
}

__device__ __forceinline__ void async16(const void* g, void* l) {
  __builtin_amdgcn_global_load_lds(
      (const __attribute__((address_space(1))) unsigned int*)g,
      (__attribute__((address_space(3))) unsigned int*)l, 16, 0, 0);
}

// ---- normalize 16 rows (one panel) -> bf16 in FRAGMENT-MAJOR layout ----
// Fragment (panel P, q): 1KB at (P*NQ+q)*512 ushorts; lane l holds
// row P*16+(l&15), k = q*32 + (l>>4)*8 + j. Optionally inits max arrays.
__global__ __launch_bounds__(512) void normf_kernel(
    const float* __restrict__ src, u16* __restrict__ dst,
    unsigned* __restrict__ enc_init) {
  const int p = blockIdx.x;
  const int t = threadIdx.x, lane = t & 63, w = t >> 6;
  const int fr = lane & 15, hi = lane >> 4;
  if (enc_init) {
    const int i = p * 512 + t;
    if (i < 2 * NROWS) enc_init[i] = fenc(-2.0f);
  }
  __shared__ float part[16][8];
  float e[2][8];
  float ss = 0.f;
#pragma unroll
  for (int c = 0; c < 2; ++c) {
    const int q = w + c * 8;
    const float* g = src + (size_t)(p * 16 + fr) * DIM + q * 32 + hi * 8;
    float4 v0 = *(const float4*)g;
    float4 v1 = *(const float4*)(g + 4);
    e[c][0] = v0.x; e[c][1] = v0.y; e[c][2] = v0.z; e[c][3] = v0.w;
    e[c][4] = v1.x; e[c][5] = v1.y; e[c][6] = v1.z; e[c][7] = v1.w;
#pragma unroll
    for (int j = 0; j < 8; ++j) ss += e[c][j] * e[c][j];
  }
  ss += __shfl_xor(ss, 16);
  ss += __shfl_xor(ss, 32);
  if (lane < 16) part[lane][w] = ss;
  __syncthreads();
  float tot = 0.f;
#pragma unroll
  for (int i = 0; i < 8; ++i) tot += part[fr][i];
  const float sc = 1.0f / fmaxf(sqrtf(tot), 1e-8f);
#pragma unroll
  for (int c = 0; c < 2; ++c) {
    const int q = w + c * 8;
    u16x8 o;
#pragma unroll
    for (int j = 0; j < 8; ++j) o[j] = f2bf(e[c][j] * sc);
    *(u16x8*)(dst + ((size_t)(p * NQ + q) * 64 + lane) * 8) = o;
  }
}

// ---- 128x128 MFMA GEMM, 4 waves, 2-slot ring, 3 blocks/CU, fused max ----
__global__ __launch_bounds__(256, 3) void gemm_max_kernel(
    const u16* __restrict__ Xf, const u16* __restrict__ Yf,
    unsigned* __restrict__ rowmax, unsigned* __restrict__ colmax) {
  __shared__ u16 lds[2][16][512];  // 32 KB: [slot][A0..7|B8..15][frag]

  const int t = threadIdx.x, lane = t & 63, w = t >> 6;
  const int wr = w >> 1, wc = w & 1;  // 2x2 wave grid; wave owns 64x64 out

  // bijective XCD swizzle: 4096 blocks (64x64 tiles); per XCD the ~96
  // resident blocks form an 8-row x 8-col supertile (A 1MB + B 1MB in L2).
  const int raw = blockIdx.x, xcd = raw & 7, l = raw >> 3;  // l: 0..511
  const int brow = ((l >> 6) * 8 + (l & 7)) * 128;
  const int bcol = (xcd * 8 + ((l >> 3) & 7)) * 128;
  const int browP = brow >> 4, bcolP = bcol >> 4;

  f32x4 acc[4][4];
#pragma unroll
  for (int m = 0; m < 4; ++m)
#pragma unroll
    for (int n = 0; n < 4; ++n) acc[m][n] = (f32x4){0.f, 0.f, 0.f, 0.f};

  // staging sources: wave w covers fragment rows {2w, 2w+1} of A and B
  const u16* gA0 = Xf + ((size_t)(browP + 2 * w) * NQ) * 512 + lane * 8;
  const u16* gA1 = Xf + ((size_t)(browP + 2 * w + 1) * NQ) * 512 + lane * 8;
  const u16* gB0 = Yf + ((size_t)(bcolP + 2 * w) * NQ) * 512 + lane * 8;
  const u16* gB1 = Yf + ((size_t)(bcolP + 2 * w + 1) * NQ) * 512 + lane * 8;

  auto stage = [&](int h, int s) {
    const size_t o = (size_t)h * 512;
    async16(gA0 + o, &lds[s][2 * w][0]);
    async16(gA1 + o, &lds[s][2 * w + 1][0]);
    async16(gB0 + o, &lds[s][8 + 2 * w][0]);
    async16(gB1 + o, &lds[s][8 + 2 * w + 1][0]);
  };

  stage(0, 0);

  // 1 barrier per K-step. vmcnt(0) covers loads issued one FULL step ago
  // (not a same-step drain). WAR on the alternate slot is safe: its reads
  // completed before the previous step's MFMA, which precedes this barrier.
#pragma unroll 2
  for (int h = 0; h < NSTEP; ++h) {
    asm volatile("s_waitcnt vmcnt(0)" ::: "memory");
    __builtin_amdgcn_s_barrier();
    if (h < NSTEP - 1) stage(h + 1, (h + 1) & 1);
    const int s = h & 1;
    bf16x8 a[4], b[4];
#pragma unroll
    for (int n = 0; n < 4; ++n)
      b[n] = *(const bf16x8*)(&lds[s][8 + wc * 4 + n][lane * 8]);
#pragma unroll
    for (int m = 0; m < 4; ++m)
      a[m] = *(const bf16x8*)(&lds[s][wr * 4 + m][lane * 8]);
#pragma unroll
    for (int m = 0; m < 4; ++m)
#pragma unroll
      for (int n = 0; n < 4; ++n)
        acc[m][n] = __builtin_amdgcn_mfma_f32_16x16x32_bf16(a[m], b[n], acc[m][n], 0, 0, 0);
  }

  // ---- epilogue: C/D layout col=lane&15, row=(lane>>4)*4+reg ----
#pragma unroll
  for (int m = 0; m < 4; ++m) {
    f32x4 rm = acc[m][0];
#pragma unroll
    for (int n = 1; n < 4; ++n) {
      rm[0] = fmaxf(rm[0], acc[m][n][0]);
      rm[1] = fmaxf(rm[1], acc[m][n][1]);
      rm[2] = fmaxf(rm[2], acc[m][n][2]);
      rm[3] = fmaxf(rm[3], acc[m][n][3]);
    }
#pragma unroll
    for (int r = 0; r < 4; ++r) {
      float v = rm[r];
      v = fmaxf(v, __shfl_xor(v, 1));
      v = fmaxf(v, __shfl_xor(v, 2));
      v = fmaxf(v, __shfl_xor(v, 4));
      v = fmaxf(v, __shfl_xor(v, 8));
      if ((lane & 15) == 0) {
        const int grow = brow + wr * 64 + m * 16 + (lane >> 4) * 4 + r;
        atomicMax(rowmax + grow, fenc(v));
      }
    }
  }
#pragma unroll
  for (int n = 0; n < 4; ++n) {
    float cm = -2.0f;
#pragma unroll
    for (int m = 0; m < 4; ++m) {
      cm = fmaxf(cm, acc[m][n][0]);
      cm = fmaxf(cm, acc[m][n][1]);
      cm = fmaxf(cm, acc[m][n][2]);
      cm = fmaxf(cm, acc[m][n][3]);
    }
    cm = fmaxf(cm, __shfl_xor(cm, 16));
    cm = fmaxf(cm, __shfl_xor(cm, 32));
    if (lane < 16) {
      const int gcol = bcol + wc * 64 + n * 16 + lane;
      atomicMax(colmax + gcol, fenc(cm));
    }
  }
}

// ---- entropy: out[b] = -sum( exp(lp)*lp ), lp = -0.5*z^2 + 0.285034... ----
__global__ __launch_bounds__(256) void entropy_kernel(
    const unsigned* __restrict__ enc, float* __restrict__ out) {
  const int which = blockIdx.x;
  const unsigned* e = enc + which * NROWS;
  float s = 0.0f;
  for (int i = threadIdx.x; i < NROWS; i += 256) {
    const float x = fdec(e[i]);
    const float z = (x - 1.0f) * (1.0f / 0.3f);
    const float lp = -0.5f * z * z + 0.2850342711439819f;
    s += expf(lp) * lp;
  }
#pragma unroll
  for (int m = 1; m <= 32; m <<= 1) s += __shfl_xor(s, m);
  __shared__ float sr[4];
  if ((threadIdx.x & 63) == 0) sr[threadIdx.x >> 6] = s;
  __syncthreads();
  if (threadIdx.x == 0) out[which] = -(sr[0] + sr[1] + sr[2] + sr[3]);
}

extern "C" void kernel_launch(void* const* d_in, const int* in_sizes, int n_in,
                              void* d_out, int out_size, void* d_ws, size_t ws_size,
                              hipStream_t stream) {
  const float* ex = (const float*)d_in[0];
  const float* ey = (const float*)d_in[1];

  u16* Xf = (u16*)d_ws;                                  // 8 MB fragment-major
  u16* Yf = Xf + (size_t)NROWS * DIM;                    // 8 MB
  unsigned* enc = (unsigned*)(Yf + (size_t)NROWS * DIM); // 2*8192 u32
  float* out = (float*)d_out;

  hipLaunchKernelGGL(normf_kernel, dim3(NROWS / 16), dim3(512), 0, stream, ex, Xf, enc);
  hipLaunchKernelGGL(normf_kernel, dim3(NROWS / 16), dim3(512), 0, stream, ey, Yf, (unsigned*)nullptr);
  hipLaunchKernelGGL(gemm_max_kernel, dim3(64 * 64), dim3(256), 0, stream,
                     Xf, Yf, enc, enc + NROWS);
  hipLaunchKernelGGL(entropy_kernel, dim3(2), dim3(256), 0, stream, enc, out);
}